// Round 1
// baseline (1910.210 us; speedup 1.0000x reference)
//
#include <hip/hip_runtime.h>
#include <math.h>

#define NEG_SLOPE 0.2f
#define EPSV 1e-16f

// float atomic max via signed-max / unsigned-min bit trick (init must be -inf)
__device__ __forceinline__ void atomicMaxF(float* addr, float val) {
    if (val >= 0.0f) {
        atomicMax((int*)addr, __float_as_int(val));
    } else {
        atomicMin((unsigned int*)addr, (unsigned int)__float_as_int(val));
    }
}

// zero the per-node accumulator [N*64], init nmax=-inf, denom=0
__global__ void k_node_init(float* __restrict__ accum, float* __restrict__ nmax,
                            float* __restrict__ denom, int N) {
    int i = blockIdx.x * 256 + threadIdx.x;
    if (i < N * 64) accum[i] = 0.0f;
    if (i < N) { nmax[i] = -INFINITY; denom[i] = 0.0f; }
}

// X [N,K] @ Wl/Wr [K,64] -> xl/xr [N,64]; 4 nodes per 256-thread block
template <int K>
__global__ void k_gemm(const float* __restrict__ X, const float* __restrict__ Wl,
                       const float* __restrict__ Wr, float* __restrict__ xl,
                       float* __restrict__ xr, int N) {
    __shared__ float xs[4][K];
    const int node0 = blockIdx.x * 4;
    const int tid = threadIdx.x;
    for (int i = tid; i < 4 * K; i += 256) {
        int n = node0 + i / K;
        xs[i / K][i % K] = (n < N) ? X[(size_t)node0 * K + i] : 0.0f;
    }
    __syncthreads();
    const int f = tid & 63;
    const int sub = tid >> 6;
    const int node = node0 + sub;
    if (node >= N) return;
    float accl = 0.0f, accr = 0.0f;
#pragma unroll 8
    for (int k = 0; k < K; ++k) {
        float xv = xs[sub][k];
        accl = fmaf(xv, Wl[k * 64 + f], accl);
        accr = fmaf(xv, Wr[k * 64 + f], accr);
    }
    xl[(size_t)node * 64 + f] = accl;
    xr[(size_t)node * 64 + f] = accr;
}

// per-edge attention logit + segment max; 16 lanes per edge
__global__ void k_logit(const float* __restrict__ xl, const float* __restrict__ xr,
                        const float* __restrict__ att, const int* __restrict__ ei,
                        int E, int ET, float* __restrict__ ebuf,
                        float* __restrict__ nmax) {
    int t = blockIdx.x * 256 + threadIdx.x;
    int edge = t >> 4;
    int lane = t & 15;
    if (edge >= ET) return;
    int src, dst;
    if (edge < E) { src = ei[edge]; dst = ei[E + edge]; }
    else          { src = dst = edge - E; }
    const float4 a = *(const float4*)(xl + (size_t)src * 64 + lane * 4);
    const float4 b = *(const float4*)(xr + (size_t)dst * 64 + lane * 4);
    const float4 w = *(const float4*)(att + lane * 4);
    float s = 0.0f, v;
    v = a.x + b.x; s += w.x * (v > 0.0f ? v : NEG_SLOPE * v);
    v = a.y + b.y; s += w.y * (v > 0.0f ? v : NEG_SLOPE * v);
    v = a.z + b.z; s += w.z * (v > 0.0f ? v : NEG_SLOPE * v);
    v = a.w + b.w; s += w.w * (v > 0.0f ? v : NEG_SLOPE * v);
    for (int off = 8; off; off >>= 1) s += __shfl_down(s, off, 16);
    if (lane == 0) {
        ebuf[edge] = s;
        atomicMaxF(&nmax[dst], s);
    }
}

// ex = exp(e - max[dst]); denom[dst] += ex; one thread per edge
__global__ void k_exp(float* __restrict__ ebuf, const float* __restrict__ nmax,
                      float* __restrict__ denom, const int* __restrict__ ei,
                      int E, int ET) {
    int edge = blockIdx.x * 256 + threadIdx.x;
    if (edge >= ET) return;
    int dst = (edge < E) ? ei[E + edge] : (edge - E);
    float ex = expf(ebuf[edge] - nmax[dst]);
    ebuf[edge] = ex;
    atomicAdd(&denom[dst], ex);
}

// out[dst,:] += (ex/denom) * xl[src,:]; 16 lanes per edge, 4 atomics/lane
__global__ void k_aggr(const float* __restrict__ ebuf, const float* __restrict__ denom,
                       const float* __restrict__ xl, const int* __restrict__ ei,
                       int E, int ET, float* __restrict__ out) {
    int t = blockIdx.x * 256 + threadIdx.x;
    int edge = t >> 4;
    int lane = t & 15;
    if (edge >= ET) return;
    int src, dst;
    if (edge < E) { src = ei[edge]; dst = ei[E + edge]; }
    else          { src = dst = edge - E; }
    float alpha = ebuf[edge] / (denom[dst] + EPSV);
    const float4 a = *(const float4*)(xl + (size_t)src * 64 + lane * 4);
    float* o = out + (size_t)dst * 64 + lane * 4;
    atomicAdd(o + 0, alpha * a.x);
    atomicAdd(o + 1, alpha * a.y);
    atomicAdd(o + 2, alpha * a.z);
    atomicAdd(o + 3, alpha * a.w);
}

// out += bias (broadcast over feature dim), optional relu
__global__ void k_bias_act(float* __restrict__ out, const float* __restrict__ bias,
                           int N, int relu) {
    int i = blockIdx.x * 256 + threadIdx.x;
    if (i >= N * 64) return;
    float v = out[i] + bias[i & 63];
    out[i] = relu ? fmaxf(v, 0.0f) : v;
}

extern "C" void kernel_launch(void* const* d_in, const int* in_sizes, int n_in,
                              void* d_out, int out_size, void* d_ws, size_t ws_size,
                              hipStream_t stream) {
    const float* x    = (const float*)d_in[0];
    const int*   ei   = (const int*)d_in[1];
    const float* W1l  = (const float*)d_in[2];
    const float* W1r  = (const float*)d_in[3];
    const float* att1 = (const float*)d_in[4];
    const float* b1   = (const float*)d_in[5];
    const float* W2l  = (const float*)d_in[6];
    const float* W2r  = (const float*)d_in[7];
    const float* att2 = (const float*)d_in[8];
    const float* b2   = (const float*)d_in[9];

    const int N  = in_sizes[0] / 128;
    const int E  = in_sizes[1] / 2;
    const int ET = E + N;   // with self loops

    float* ws    = (float*)d_ws;
    float* xl    = ws;                       // N*64
    float* xr    = xl + (size_t)N * 64;      // N*64
    float* h     = xr + (size_t)N * 64;      // N*64
    float* ebuf  = h + (size_t)N * 64;       // ET
    float* nmax  = ebuf + ET;                // N
    float* denom = nmax + N;                 // N
    float* out   = (float*)d_out;

    const dim3 b256(256);
    const int gNode   = (N * 64 + 255) / 256;
    const int gEdge16 = (ET * 16 + 255) / 256;
    const int gEdge   = (ET + 255) / 256;
    const int gGemm   = (N + 3) / 4;

    // ---- Layer 1 ----
    k_node_init<<<gNode, b256, 0, stream>>>(h, nmax, denom, N);
    k_gemm<128><<<gGemm, b256, 0, stream>>>(x, W1l, W1r, xl, xr, N);
    k_logit<<<gEdge16, b256, 0, stream>>>(xl, xr, att1, ei, E, ET, ebuf, nmax);
    k_exp<<<gEdge, b256, 0, stream>>>(ebuf, nmax, denom, ei, E, ET);
    k_aggr<<<gEdge16, b256, 0, stream>>>(ebuf, denom, xl, ei, E, ET, h);
    k_bias_act<<<gNode, b256, 0, stream>>>(h, b1, N, 1);

    // ---- Layer 2 ----
    k_node_init<<<gNode, b256, 0, stream>>>(out, nmax, denom, N);
    k_gemm<64><<<gGemm, b256, 0, stream>>>(h, W2l, W2r, xl, xr, N);
    k_logit<<<gEdge16, b256, 0, stream>>>(xl, xr, att2, ei, E, ET, ebuf, nmax);
    k_exp<<<gEdge, b256, 0, stream>>>(ebuf, nmax, denom, ei, E, ET);
    k_aggr<<<gEdge16, b256, 0, stream>>>(ebuf, denom, xl, ei, E, ET, out);
    k_bias_act<<<gNode, b256, 0, stream>>>(out, b2, N, 0);
}

// Round 2
// 548.318 us; speedup vs baseline: 3.4838x; 3.4838x over previous
//
#include <hip/hip_runtime.h>
#include <math.h>

#define NEG_SLOPE 0.2f
#define EPSV 1e-16f

// ---------------- CSR build ----------------

__global__ void k_zero_i(int* __restrict__ p, int n) {
    int i = blockIdx.x * 256 + threadIdx.x;
    if (i < n) p[i] = 0;
}

// histogram of incoming-edge counts per dst (self loops appended)
__global__ void k_hist(const int* __restrict__ ei, int E, int ET,
                       int* __restrict__ cnt) {
    int e = blockIdx.x * 256 + threadIdx.x;
    if (e >= ET) return;
    int dst = (e < E) ? ei[E + e] : (e - E);
    atomicAdd(&cnt[dst], 1);
}

// per-1024-chunk totals (grid = ceil(N/1024), block 256, 4 elems/thread)
__global__ void k_scan1(const int* __restrict__ cnt, int N, int* __restrict__ bsum) {
    __shared__ int sh[256];
    const int b = blockIdx.x, t = threadIdx.x;
    const int base = b * 1024 + t * 4;
    int s = 0;
#pragma unroll
    for (int i = 0; i < 4; ++i) { int idx = base + i; if (idx < N) s += cnt[idx]; }
    sh[t] = s; __syncthreads();
    for (int d = 128; d; d >>= 1) {
        if (t < d) sh[t] += sh[t + d];
        __syncthreads();
    }
    if (t == 0) bsum[b] = sh[0];
}

// serial exclusive scan of chunk totals (nb <= ~64); also writes off[N]=total
__global__ void k_scan2(int* __restrict__ bsum, int nb, int* __restrict__ off, int N) {
    int run = 0;
    for (int i = 0; i < nb; ++i) { int v = bsum[i]; bsum[i] = run; run += v; }
    off[N] = run;
}

// per-chunk exclusive scan + chunk offset -> off[0..N)
__global__ void k_scan3(const int* __restrict__ cnt, int N,
                        const int* __restrict__ bsum, int* __restrict__ off) {
    __shared__ int sh[256];
    const int b = blockIdx.x, t = threadIdx.x;
    const int base = b * 1024 + t * 4;
    int v[4]; int s = 0;
#pragma unroll
    for (int i = 0; i < 4; ++i) {
        int idx = base + i;
        v[i] = (idx < N) ? cnt[idx] : 0;
        s += v[i];
    }
    sh[t] = s; __syncthreads();
    for (int d = 1; d < 256; d <<= 1) {
        int add = (t >= d) ? sh[t - d] : 0;
        __syncthreads();
        sh[t] += add;
        __syncthreads();
    }
    int ex = bsum[b] + sh[t] - s;   // exclusive prefix for this thread's first elem
#pragma unroll
    for (int i = 0; i < 4; ++i) {
        int idx = base + i;
        if (idx < N) off[idx] = ex;
        ex += v[i];
    }
}

// scatter src ids into CSR slots (cur must be zeroed)
__global__ void k_scatter(const int* __restrict__ ei, int E, int ET,
                          const int* __restrict__ off, int* __restrict__ cur,
                          int* __restrict__ csrc) {
    int e = blockIdx.x * 256 + threadIdx.x;
    if (e >= ET) return;
    int src, dst;
    if (e < E) { src = ei[e]; dst = ei[E + e]; }
    else       { src = dst = e - E; }
    int p = off[dst] + atomicAdd(&cur[dst], 1);
    csrc[p] = src;
}

// ---------------- dense transforms ----------------

// X [N,K] @ Wl/Wr [K,64] -> xl/xr [N,64]; 4 nodes per 256-thread block
template <int K>
__global__ void k_gemm(const float* __restrict__ X, const float* __restrict__ Wl,
                       const float* __restrict__ Wr, float* __restrict__ xl,
                       float* __restrict__ xr, int N) {
    __shared__ float xs[4][K];
    const int node0 = blockIdx.x * 4;
    const int tid = threadIdx.x;
    for (int i = tid; i < 4 * K; i += 256) {
        int n = node0 + i / K;
        xs[i / K][i % K] = (n < N) ? X[(size_t)node0 * K + i] : 0.0f;
    }
    __syncthreads();
    const int f = tid & 63;
    const int sub = tid >> 6;
    const int node = node0 + sub;
    if (node >= N) return;
    float accl = 0.0f, accr = 0.0f;
#pragma unroll 8
    for (int k = 0; k < K; ++k) {
        float xv = xs[sub][k];
        accl = fmaf(xv, Wl[k * 64 + f], accl);
        accr = fmaf(xv, Wr[k * 64 + f], accr);
    }
    xl[(size_t)node * 64 + f] = accl;
    xr[(size_t)node * 64 + f] = accr;
}

// ---------------- fused attention (one wave per dst node) ----------------
// logit + online softmax + weighted aggregation + bias (+relu), no atomics
__global__ void k_attn(const float* __restrict__ xl, const float* __restrict__ xr,
                       const float* __restrict__ att, const int* __restrict__ off,
                       const int* __restrict__ csrc, const float* __restrict__ bias,
                       float* __restrict__ out, int N, int relu) {
    const int lane = threadIdx.x & 63;
    const int dst = blockIdx.x * 4 + (threadIdx.x >> 6);
    if (dst >= N) return;
    const float xrv = xr[(size_t)dst * 64 + lane];
    const float aw = att[lane];
    const int e0 = off[dst], e1 = off[dst + 1];
    float m = -INFINITY, l = 0.0f, acc = 0.0f;
    for (int e = e0; e < e1; ++e) {
        int src = csrc[e];
        float v = xl[(size_t)src * 64 + lane];
        float t = v + xrv;
        t = (t > 0.0f) ? t : NEG_SLOPE * t;
        float p = t * aw;
#pragma unroll
        for (int o = 32; o; o >>= 1) p += __shfl_xor(p, o, 64);
        float mnew = fmaxf(m, p);
        float scale = expf(m - mnew);      // 0 on first iter (m=-inf)
        float w = expf(p - mnew);
        l = l * scale + w;
        acc = acc * scale + w * v;
        m = mnew;
    }
    float res = acc / (l + EPSV) + bias[lane];
    if (relu) res = fmaxf(res, 0.0f);
    out[(size_t)dst * 64 + lane] = res;
}

// ---------------- launch ----------------

extern "C" void kernel_launch(void* const* d_in, const int* in_sizes, int n_in,
                              void* d_out, int out_size, void* d_ws, size_t ws_size,
                              hipStream_t stream) {
    const float* x    = (const float*)d_in[0];
    const int*   ei   = (const int*)d_in[1];
    const float* W1l  = (const float*)d_in[2];
    const float* W1r  = (const float*)d_in[3];
    const float* att1 = (const float*)d_in[4];
    const float* b1   = (const float*)d_in[5];
    const float* W2l  = (const float*)d_in[6];
    const float* W2r  = (const float*)d_in[7];
    const float* att2 = (const float*)d_in[8];
    const float* b2   = (const float*)d_in[9];

    const int N  = in_sizes[0] / 128;
    const int E  = in_sizes[1] / 2;
    const int ET = E + N;               // with self loops
    const int NB = (N + 1023) / 1024;   // scan chunks

    int* wsi   = (int*)d_ws;
    int* off   = wsi;                   // N+1
    int* cnt   = off + (N + 1);         // N (histogram, then reused as cursor)
    int* bsum  = cnt + N;               // NB (pad 128)
    int* csrc  = bsum + 128;            // ET
    float* xl  = (float*)(csrc + ET);   // N*64
    float* xr  = xl + (size_t)N * 64;   // N*64
    float* h   = xr + (size_t)N * 64;   // N*64
    float* out = (float*)d_out;

    const dim3 b256(256);
    const int gEdge = (ET + 255) / 256;
    const int gN    = (N + 255) / 256;
    const int gGemm = (N + 3) / 4;
    const int gAttn = (N + 3) / 4;

    // ---- CSR build (shared by both layers) ----
    k_zero_i<<<gN, b256, 0, stream>>>(cnt, N);
    k_hist<<<gEdge, b256, 0, stream>>>(ei, E, ET, cnt);
    k_scan1<<<NB, b256, 0, stream>>>(cnt, N, bsum);
    k_scan2<<<1, 1, 0, stream>>>(bsum, NB, off, N);
    k_scan3<<<NB, b256, 0, stream>>>(cnt, N, bsum, off);
    k_zero_i<<<gN, b256, 0, stream>>>(cnt, N);        // reuse as scatter cursor
    k_scatter<<<gEdge, b256, 0, stream>>>(ei, E, ET, off, cnt, csrc);

    // ---- Layer 1 ----
    k_gemm<128><<<gGemm, b256, 0, stream>>>(x, W1l, W1r, xl, xr, N);
    k_attn<<<gAttn, b256, 0, stream>>>(xl, xr, att1, off, csrc, b1, h, N, 1);

    // ---- Layer 2 ----
    k_gemm<64><<<gGemm, b256, 0, stream>>>(h, W2l, W2r, xl, xr, N);
    k_attn<<<gAttn, b256, 0, stream>>>(xl, xr, att2, off, csrc, b2, out, N, 0);
}

// Round 3
// 334.975 us; speedup vs baseline: 5.7025x; 1.6369x over previous
//
#include <hip/hip_runtime.h>
#include <math.h>

#define NEG_SLOPE 0.2f
#define EPSV 1e-16f
#define NEG_HUGE -1e30f

// ---------------- CSR build ----------------

__global__ void k_zero_i(int* __restrict__ p, int n) {
    int i = blockIdx.x * 256 + threadIdx.x;
    if (i < n) p[i] = 0;
}

// histogram of incoming-edge counts per dst (self loops appended)
__global__ void k_hist(const int* __restrict__ ei, int E, int ET,
                       int* __restrict__ cnt) {
    int e = blockIdx.x * 256 + threadIdx.x;
    if (e >= ET) return;
    int dst = (e < E) ? ei[E + e] : (e - E);
    atomicAdd(&cnt[dst], 1);
}

// per-1024-chunk totals (grid = ceil(N/1024), block 256, 4 elems/thread)
__global__ void k_scan1(const int* __restrict__ cnt, int N, int* __restrict__ bsum) {
    __shared__ int sh[256];
    const int b = blockIdx.x, t = threadIdx.x;
    const int base = b * 1024 + t * 4;
    int s = 0;
#pragma unroll
    for (int i = 0; i < 4; ++i) { int idx = base + i; if (idx < N) s += cnt[idx]; }
    sh[t] = s; __syncthreads();
    for (int d = 128; d; d >>= 1) {
        if (t < d) sh[t] += sh[t + d];
        __syncthreads();
    }
    if (t == 0) bsum[b] = sh[0];
}

// parallel exclusive scan of chunk totals (nb <= 256); writes off[N]=total
__global__ void k_scan2(int* __restrict__ bsum, int nb, int* __restrict__ off, int N) {
    __shared__ int sh[256];
    const int t = threadIdx.x;
    int v = (t < nb) ? bsum[t] : 0;
    sh[t] = v; __syncthreads();
    for (int d = 1; d < 256; d <<= 1) {
        int add = (t >= d) ? sh[t - d] : 0;
        __syncthreads();
        sh[t] += add;
        __syncthreads();
    }
    if (t < nb) bsum[t] = sh[t] - v;        // exclusive
    if (t == 255) off[N] = sh[255];
}

// per-chunk exclusive scan + chunk offset -> off[0..N)
__global__ void k_scan3(const int* __restrict__ cnt, int N,
                        const int* __restrict__ bsum, int* __restrict__ off) {
    __shared__ int sh[256];
    const int b = blockIdx.x, t = threadIdx.x;
    const int base = b * 1024 + t * 4;
    int v[4]; int s = 0;
#pragma unroll
    for (int i = 0; i < 4; ++i) {
        int idx = base + i;
        v[i] = (idx < N) ? cnt[idx] : 0;
        s += v[i];
    }
    sh[t] = s; __syncthreads();
    for (int d = 1; d < 256; d <<= 1) {
        int add = (t >= d) ? sh[t - d] : 0;
        __syncthreads();
        sh[t] += add;
        __syncthreads();
    }
    int ex = bsum[b] + sh[t] - s;
#pragma unroll
    for (int i = 0; i < 4; ++i) {
        int idx = base + i;
        if (idx < N) off[idx] = ex;
        ex += v[i];
    }
}

// scatter src ids into CSR slots (cur must be zeroed)
__global__ void k_scatter(const int* __restrict__ ei, int E, int ET,
                          const int* __restrict__ off, int* __restrict__ cur,
                          int* __restrict__ csrc) {
    int e = blockIdx.x * 256 + threadIdx.x;
    if (e >= ET) return;
    int src, dst;
    if (e < E) { src = ei[e]; dst = ei[E + e]; }
    else       { src = dst = e - E; }
    int p = off[dst] + atomicAdd(&cur[dst], 1);
    csrc[p] = src;
}

// ---------------- dense transforms ----------------
// X [N,K] @ Wl/Wr [K,64] -> xl/xr [N,64]; 16 nodes per 256-thread block,
// each thread computes 4 nodes x 1 feature (W-load amortized over 8 FMAs)
template <int K>
__global__ void k_gemm(const float* __restrict__ X, const float* __restrict__ Wl,
                       const float* __restrict__ Wr, float* __restrict__ xl,
                       float* __restrict__ xr, int N) {
    __shared__ float xs[16][K];
    const int n0 = blockIdx.x * 16;
    const int tid = threadIdx.x;
    // stage 16 rows of X (vectorized, conflict-free)
    float4* xs4 = (float4*)&xs[0][0];
    const int total4 = 16 * K / 4;
    for (int idx = tid; idx < total4; idx += 256) {
        int n = (idx * 4) / K;
        float4 val = {0.0f, 0.0f, 0.0f, 0.0f};
        if (n0 + n < N) val = *(const float4*)(X + (size_t)n0 * K + idx * 4);
        xs4[idx] = val;
    }
    __syncthreads();
    const int f = tid & 63;
    const int g = tid >> 6;            // wave id; handles nodes n0+4g..n0+4g+3
    float accl[4] = {0, 0, 0, 0}, accr[4] = {0, 0, 0, 0};
#pragma unroll 8
    for (int k = 0; k < K; ++k) {
        const float wl = Wl[k * 64 + f];
        const float wr = Wr[k * 64 + f];
#pragma unroll
        for (int j = 0; j < 4; ++j) {
            float xv = xs[4 * g + j][k];   // wave-uniform address -> LDS broadcast
            accl[j] = fmaf(xv, wl, accl[j]);
            accr[j] = fmaf(xv, wr, accr[j]);
        }
    }
#pragma unroll
    for (int j = 0; j < 4; ++j) {
        int node = n0 + 4 * g + j;
        if (node < N) {
            xl[(size_t)node * 64 + f] = accl[j];
            xr[(size_t)node * 64 + f] = accr[j];
        }
    }
}

// ---------------- fused attention (one wave per dst, 4 edges/iter) ----------
// lane = g*16+i : group g handles edge slot e0+t+g, lane i holds features 4i..4i+3
__global__ void k_attn(const float* __restrict__ xl, const float* __restrict__ xr,
                       const float* __restrict__ att, const int* __restrict__ off,
                       const int* __restrict__ csrc, const float* __restrict__ bias,
                       float* __restrict__ out, int N, int relu) {
    const int lane = threadIdx.x & 63;
    const int g = lane >> 4;
    const int i = lane & 15;
    const int dst = blockIdx.x * 4 + (threadIdx.x >> 6);
    if (dst >= N) return;
    const float4 xrv = *(const float4*)(xr + (size_t)dst * 64 + i * 4);
    const float4 aw  = *(const float4*)(att + i * 4);
    const int e0 = off[dst];
    const int deg = off[dst + 1] - e0;
    float m = NEG_HUGE, l = 0.0f;
    float4 acc = {0.0f, 0.0f, 0.0f, 0.0f};
    for (int t = 0; t < deg; t += 4) {
        const bool valid = (t + g) < deg;
        const int esafe = valid ? (e0 + t + g) : e0;
        const int src = csrc[esafe];
        const float4 v = *(const float4*)(xl + (size_t)src * 64 + i * 4);
        float4 tv;
        tv.x = v.x + xrv.x; tv.x = tv.x > 0.0f ? tv.x : NEG_SLOPE * tv.x;
        tv.y = v.y + xrv.y; tv.y = tv.y > 0.0f ? tv.y : NEG_SLOPE * tv.y;
        tv.z = v.z + xrv.z; tv.z = tv.z > 0.0f ? tv.z : NEG_SLOPE * tv.z;
        tv.w = v.w + xrv.w; tv.w = tv.w > 0.0f ? tv.w : NEG_SLOPE * tv.w;
        float p = aw.x * tv.x;
        p = fmaf(aw.y, tv.y, p);
        p = fmaf(aw.z, tv.z, p);
        p = fmaf(aw.w, tv.w, p);
        // reduce the 16 lanes of each group (all 4 edges reduced by one chain)
        p += __shfl_xor(p, 1, 64);
        p += __shfl_xor(p, 2, 64);
        p += __shfl_xor(p, 4, 64);
        p += __shfl_xor(p, 8, 64);
        p = valid ? p : NEG_HUGE;
        // online softmax update (per group; dead groups stay finite and are
        // zeroed at merge by exp(NEG_HUGE - m_real) == 0)
        const float mnew = fmaxf(m, p);
        const float s = expf(m - mnew);
        const float d = expf(p - mnew);
        l = l * s + d;
        acc.x = fmaf(acc.x, s, d * v.x);
        acc.y = fmaf(acc.y, s, d * v.y);
        acc.z = fmaf(acc.z, s, d * v.z);
        acc.w = fmaf(acc.w, s, d * v.w);
        m = mnew;
    }
    // merge the 4 groups' softmax states (xor 16, then 32)
#pragma unroll
    for (int o = 16; o <= 32; o <<= 1) {
        const float m2 = __shfl_xor(m, o, 64);
        const float l2 = __shfl_xor(l, o, 64);
        float4 a2;
        a2.x = __shfl_xor(acc.x, o, 64);
        a2.y = __shfl_xor(acc.y, o, 64);
        a2.z = __shfl_xor(acc.z, o, 64);
        a2.w = __shfl_xor(acc.w, o, 64);
        const float mn = fmaxf(m, m2);
        const float s1 = expf(m - mn);
        const float s2 = expf(m2 - mn);
        l = l * s1 + l2 * s2;
        acc.x = acc.x * s1 + a2.x * s2;
        acc.y = acc.y * s1 + a2.y * s2;
        acc.z = acc.z * s1 + a2.z * s2;
        acc.w = acc.w * s1 + a2.w * s2;
        m = mn;
    }
    if (g == 0) {
        const float4 bv = *(const float4*)(bias + i * 4);
        const float inv = 1.0f / (l + EPSV);
        float4 r;
        r.x = fmaf(acc.x, inv, bv.x);
        r.y = fmaf(acc.y, inv, bv.y);
        r.z = fmaf(acc.z, inv, bv.z);
        r.w = fmaf(acc.w, inv, bv.w);
        if (relu) {
            r.x = fmaxf(r.x, 0.0f); r.y = fmaxf(r.y, 0.0f);
            r.z = fmaxf(r.z, 0.0f); r.w = fmaxf(r.w, 0.0f);
        }
        *(float4*)(out + (size_t)dst * 64 + i * 4) = r;
    }
}

// ---------------- launch ----------------

extern "C" void kernel_launch(void* const* d_in, const int* in_sizes, int n_in,
                              void* d_out, int out_size, void* d_ws, size_t ws_size,
                              hipStream_t stream) {
    const float* x    = (const float*)d_in[0];
    const int*   ei   = (const int*)d_in[1];
    const float* W1l  = (const float*)d_in[2];
    const float* W1r  = (const float*)d_in[3];
    const float* att1 = (const float*)d_in[4];
    const float* b1   = (const float*)d_in[5];
    const float* W2l  = (const float*)d_in[6];
    const float* W2r  = (const float*)d_in[7];
    const float* att2 = (const float*)d_in[8];
    const float* b2   = (const float*)d_in[9];

    const int N  = in_sizes[0] / 128;
    const int E  = in_sizes[1] / 2;
    const int ET = E + N;               // with self loops
    const int NB = (N + 1023) / 1024;   // scan chunks (<=256)

    int* wsi   = (int*)d_ws;
    int* off   = wsi;                   // N+1
    int* cnt   = off + (N + 1);         // N histogram
    int* cur   = cnt + N;               // N scatter cursor
    int* bsum  = cur + N;               // 256
    int* csrc  = bsum + 256;            // ET
    float* xl  = (float*)(csrc + ET);   // N*64
    float* xr  = xl + (size_t)N * 64;   // N*64
    float* h   = xr + (size_t)N * 64;   // N*64
    float* out = (float*)d_out;

    const dim3 b256(256);
    const int gEdge = (ET + 255) / 256;
    const int gZero = (2 * N + 255) / 256;
    const int gGemm = (N + 15) / 16;
    const int gAttn = (N + 3) / 4;

    // ---- CSR build (shared by both layers) ----
    k_zero_i<<<gZero, b256, 0, stream>>>(cnt, 2 * N);     // cnt + cur adjacent
    k_hist<<<gEdge, b256, 0, stream>>>(ei, E, ET, cnt);
    k_scan1<<<NB, b256, 0, stream>>>(cnt, N, bsum);
    k_scan2<<<1, b256, 0, stream>>>(bsum, NB, off, N);
    k_scan3<<<NB, b256, 0, stream>>>(cnt, N, bsum, off);
    k_scatter<<<gEdge, b256, 0, stream>>>(ei, E, ET, off, cur, csrc);

    // ---- Layer 1 ----
    k_gemm<128><<<gGemm, b256, 0, stream>>>(x, W1l, W1r, xl, xr, N);
    k_attn<<<gAttn, b256, 0, stream>>>(xl, xr, att1, off, csrc, b1, h, N, 1);

    // ---- Layer 2 ----
    k_gemm<64><<<gGemm, b256, 0, stream>>>(h, W2l, W2r, xl, xr, N);
    k_attn<<<gAttn, b256, 0, stream>>>(xl, xr, att2, off, csrc, b2, out, N, 0);
}